// Round 1
// baseline (266.707 us; speedup 1.0000x reference)
//
#include <hip/hip_runtime.h>

#define Bv 16
#define Cv 64
#define Sv 2048
#define LOG2S 11

// ---------------------------------------------------------------------------
// Kernel 1: per-channel analytic-signal imaginary part (Hilbert transform)
// via in-LDS radix-2 FFT roundtrip. One block per channel (B*C = 1024).
// ---------------------------------------------------------------------------
__global__ __launch_bounds__(256) void hilbert_kernel(const float* __restrict__ x,
                                                      float* __restrict__ y) {
    __shared__ float re[Sv];
    __shared__ float im[Sv];
    const int ch = blockIdx.x;                 // b*Cv + c
    const float* xc = x + (size_t)ch * Sv;
    const int t = threadIdx.x;

    // Load input in bit-reversed order (DIT wants bit-reversed input).
    for (int n = t; n < Sv; n += 256) {
        int r = (int)(__brev((unsigned)n) >> (32 - LOG2S));
        re[n] = xc[r];
        im[n] = 0.0f;
    }
    __syncthreads();

    // Forward FFT (e^{-2*pi*i*k*n/N})
    for (int len = 2; len <= Sv; len <<= 1) {
        const int half = len >> 1;
        const float base = -6.283185307179586f / (float)len;
        for (int q = t; q < Sv / 2; q += 256) {
            const int pos = q & (half - 1);
            const int i0 = 2 * q - pos;        // group*len + pos
            const int i1 = i0 + half;
            float sn, cs;
            sincosf(base * (float)pos, &sn, &cs);
            const float vr = re[i1], vi = im[i1];
            const float tr = vr * cs - vi * sn;
            const float ti = vr * sn + vi * cs;
            const float ur = re[i0], ui = im[i0];
            re[i0] = ur + tr; im[i0] = ui + ti;
            re[i1] = ur - tr; im[i1] = ui - ti;
        }
        __syncthreads();
    }

    // Hilbert analytic-signal multiplier: h[0]=1, h[N/2]=1, h[1..N/2-1]=2, rest 0
    for (int k = t; k < Sv; k += 256) {
        const float m = (k == 0 || k == Sv / 2) ? 1.0f : (k < Sv / 2 ? 2.0f : 0.0f);
        re[k] *= m;
        im[k] *= m;
    }
    __syncthreads();

    // In-place bit-reverse permutation (involution): natural -> bit-reversed
    for (int n = t; n < Sv; n += 256) {
        const int r = (int)(__brev((unsigned)n) >> (32 - LOG2S));
        if (r > n) {
            float a;
            a = re[n]; re[n] = re[r]; re[r] = a;
            a = im[n]; im[n] = im[r]; im[r] = a;
        }
    }
    __syncthreads();

    // Inverse FFT (e^{+2*pi*i*k*n/N}), scale 1/N at the end
    for (int len = 2; len <= Sv; len <<= 1) {
        const int half = len >> 1;
        const float base = 6.283185307179586f / (float)len;
        for (int q = t; q < Sv / 2; q += 256) {
            const int pos = q & (half - 1);
            const int i0 = 2 * q - pos;
            const int i1 = i0 + half;
            float sn, cs;
            sincosf(base * (float)pos, &sn, &cs);
            const float vr = re[i1], vi = im[i1];
            const float tr = vr * cs - vi * sn;
            const float ti = vr * sn + vi * cs;
            const float ur = re[i0], ui = im[i0];
            re[i0] = ur + tr; im[i0] = ui + ti;
            re[i1] = ur - tr; im[i1] = ui - ti;
        }
        __syncthreads();
    }

    // y = Im(analytic) = Im(ifft)/N  (Re(analytic) == x exactly; reuse input later)
    for (int n = t; n < Sv; n += 256) {
        y[(size_t)ch * Sv + n] = im[n] * (1.0f / (float)Sv);
    }
}

// ---------------------------------------------------------------------------
// Kernel 2: PLI pair counts. One block per (b, i); 256 threads = 64 j-values
// x 4 s-slices. sign(sin(theta_i - theta_j)) == sign(y_i*x_j - x_i*y_j).
// ---------------------------------------------------------------------------
__global__ __launch_bounds__(256) void pli_kernel(const float* __restrict__ x,
                                                  const float* __restrict__ y,
                                                  float* __restrict__ out) {
    __shared__ __align__(16) float xi[Sv];
    __shared__ __align__(16) float yi[Sv];
    const int blk = blockIdx.x;                // b*Cv + i
    const int b = blk >> 6;
    const int i = blk & 63;
    const float* xb = x + (size_t)b * Cv * Sv;
    const float* yb = y + (size_t)b * Cv * Sv;
    const int t = threadIdx.x;

    for (int n = t; n < Sv; n += 256) {
        xi[n] = xb[(size_t)i * Sv + n];
        yi[n] = yb[(size_t)i * Sv + n];
    }
    __syncthreads();

    const int jj = t >> 2;                     // 0..63: which j-channel
    const int sl = t & 3;                      // 0..3: which s-slice (512 each)

    const float4* __restrict__ xj4 = (const float4*)(xb + (size_t)jj * Sv) + sl * 128;
    const float4* __restrict__ yj4 = (const float4*)(yb + (size_t)jj * Sv) + sl * 128;
    const float4* __restrict__ xi4 = (const float4*)xi + sl * 128;
    const float4* __restrict__ yi4 = (const float4*)yi + sl * 128;

    int acc = 0;
    for (int k = 0; k < 128; ++k) {
        const float4 a = xj4[k];   // x_j
        const float4 c = yj4[k];   // y_j
        const float4 u = xi4[k];   // x_i
        const float4 v = yi4[k];   // y_i
        float cr;
        cr = v.x * a.x - u.x * c.x; acc += (cr > 0.0f) - (cr < 0.0f);
        cr = v.y * a.y - u.y * c.y; acc += (cr > 0.0f) - (cr < 0.0f);
        cr = v.z * a.z - u.z * c.z; acc += (cr > 0.0f) - (cr < 0.0f);
        cr = v.w * a.w - u.w * c.w; acc += (cr > 0.0f) - (cr < 0.0f);
    }

    // fold the 4 s-slices (adjacent lanes) together
    acc += __shfl_xor(acc, 1);
    acc += __shfl_xor(acc, 2);

    if (sl == 0) {
        // diagonal must be exactly 0 (reference: sign(sin(0)) == 0); FMA
        // contraction can leave a signed residual on y_i*x_i - x_i*y_i.
        const float val = (jj == i) ? 0.0f
                                    : fabsf((float)acc) * (1.0f / (float)Sv);
        out[(size_t)blk * Cv + jj] = val;
    }
}

extern "C" void kernel_launch(void* const* d_in, const int* in_sizes, int n_in,
                              void* d_out, int out_size, void* d_ws, size_t ws_size,
                              hipStream_t stream) {
    const float* x = (const float*)d_in[0];        // [B, C, S] fp32
    float* y = (float*)d_ws;                       // [B, C, S] fp32 scratch (8 MB)
    float* out = (float*)d_out;                    // [B, C, C] fp32

    hipLaunchKernelGGL(hilbert_kernel, dim3(Bv * Cv), dim3(256), 0, stream, x, y);
    hipLaunchKernelGGL(pli_kernel, dim3(Bv * Cv), dim3(256), 0, stream, x, y, out);
}

// Round 2
// 120.503 us; speedup vs baseline: 2.2133x; 2.2133x over previous
//
#include <hip/hip_runtime.h>

#define Bv 16
#define Cv 64
#define Sv 2048
#define LOG2S 11
#define SEG 16
#define SS 128            // samples per pli segment
#define ROWF2 17          // LDS row stride in float2 (16 channels + 1 pad)

// ---------------------------------------------------------------------------
// Kernel 1: per-channel analytic-signal imaginary part (Hilbert transform)
// via in-LDS radix-2 FFT roundtrip with a precomputed LDS twiddle table.
// Also zeroes the sign-count accumulator (d_out is reused as the counter).
// One block per channel (B*C = 1024).
// ---------------------------------------------------------------------------
__global__ __launch_bounds__(256) void hilbert_kernel(const float* __restrict__ x,
                                                      float* __restrict__ y,
                                                      float* __restrict__ out_acc) {
    __shared__ float re[Sv];
    __shared__ float im[Sv];
    // Stage-concatenated twiddles: Wt[half + pos] = exp(-i*pi*pos/half),
    // pos in [0, half). Consecutive pos -> consecutive float2 -> no conflicts.
    __shared__ float2 Wt[2048];

    const int ch = blockIdx.x;                 // b*Cv + c
    const float* xc = x + (size_t)ch * Sv;
    const int t = threadIdx.x;

    // zero the per-pair accumulator (64 entries per block covers B*C*C)
    if (t < 64) out_acc[ch * 64 + t] = 0.0f;

    // fill twiddle table (entry 0 unused)
    for (int k = t; k < 2048; k += 256) {
        if (k == 0) continue;
        const int half = 1 << (31 - __clz(k));
        const int pos = k - half;
        float sn, cs;
        sincosf(-3.14159265358979323846f * (float)pos / (float)half, &sn, &cs);
        Wt[k] = make_float2(cs, sn);
    }

    // Load input in bit-reversed order (DIT wants bit-reversed input).
    for (int n = t; n < Sv; n += 256) {
        const int r = (int)(__brev((unsigned)n) >> (32 - LOG2S));
        re[n] = xc[r];
        im[n] = 0.0f;
    }
    __syncthreads();

    // Forward FFT (twiddle = Wt as stored)
    for (int half = 1; half < Sv; half <<= 1) {
        for (int q = t; q < Sv / 2; q += 256) {
            const int pos = q & (half - 1);
            const int i0 = 2 * q - pos;
            const int i1 = i0 + half;
            const float2 w = Wt[half + pos];
            const float vr = re[i1], vi = im[i1];
            const float tr = vr * w.x - vi * w.y;
            const float ti = vr * w.y + vi * w.x;
            const float ur = re[i0], ui = im[i0];
            re[i0] = ur + tr; im[i0] = ui + ti;
            re[i1] = ur - tr; im[i1] = ui - ti;
        }
        __syncthreads();
    }

    // Hilbert analytic-signal multiplier: h[0]=1, h[N/2]=1, h[1..N/2-1]=2, rest 0
    for (int k = t; k < Sv; k += 256) {
        const float m = (k == 0 || k == Sv / 2) ? 1.0f : (k < Sv / 2 ? 2.0f : 0.0f);
        re[k] *= m;
        im[k] *= m;
    }
    __syncthreads();

    // In-place bit-reverse permutation: natural -> bit-reversed
    for (int n = t; n < Sv; n += 256) {
        const int r = (int)(__brev((unsigned)n) >> (32 - LOG2S));
        if (r > n) {
            float a;
            a = re[n]; re[n] = re[r]; re[r] = a;
            a = im[n]; im[n] = im[r]; im[r] = a;
        }
    }
    __syncthreads();

    // Inverse FFT: twiddle = conj(Wt)
    for (int half = 1; half < Sv; half <<= 1) {
        for (int q = t; q < Sv / 2; q += 256) {
            const int pos = q & (half - 1);
            const int i0 = 2 * q - pos;
            const int i1 = i0 + half;
            const float2 w = Wt[half + pos];
            const float vr = re[i1], vi = im[i1];
            const float tr = vr * w.x + vi * w.y;      // conj: cos, -sin
            const float ti = -vr * w.y + vi * w.x;
            const float ur = re[i0], ui = im[i0];
            re[i0] = ur + tr; im[i0] = ui + ti;
            re[i1] = ur - tr; im[i1] = ui - ti;
        }
        __syncthreads();
    }

    // y = Im(analytic) = Im(ifft)/N  (Re(analytic) == x exactly; x reused later)
    for (int n = t; n < Sv; n += 256) {
        y[(size_t)ch * Sv + n] = im[n] * (1.0f / (float)Sv);
    }
}

// ---------------------------------------------------------------------------
// Kernel 2: PLI negative-sign counts, GEMM-style tiled.
// Grid = B * 4(it) * 4(jt) * 16(seg); block = 256 = 16 i x 16 j pairs.
// Stages 16 i-channels and 16 j-channels x 128 samples into LDS as
// [s][ch] float2 {x, y}, row padded to 17 float2 (conflict-free b64 reads:
// all lanes share s; 16 even-bank addresses, 4-way broadcast).
// sign(sin(theta_i - theta_j)) == sign(y_i*x_j - x_i*y_j).
// Accumulates neg-counts into out_acc (d_out) via float atomicAdd.
// ---------------------------------------------------------------------------
__global__ __launch_bounds__(256) void pli_count_kernel(const float* __restrict__ x,
                                                        const float* __restrict__ y,
                                                        float* __restrict__ out_acc) {
    __shared__ float2 iL[SS * ROWF2];
    __shared__ float2 jL[SS * ROWF2];

    const int blk = blockIdx.x;
    const int seg = blk & 15;
    const int jt  = (blk >> 4) & 3;
    const int it  = (blk >> 6) & 3;
    const int b   = blk >> 8;
    const int t = threadIdx.x;

    const float* xb = x + (size_t)b * Cv * Sv;
    const float* yb = y + (size_t)b * Cv * Sv;
    const int s0 = seg * SS;

    // Stage: e = ch*128 + s; within a wave s is lane-consecutive, ch constant
    // -> coalesced global scalar loads; LDS b64 writes stride 34 dwords (~2-way).
    for (int e = t; e < 16 * SS; e += 256) {
        const int ch = e >> 7;                 // 0..15
        const int s  = e & (SS - 1);
        const size_t gi = (size_t)(it * 16 + ch) * Sv + s0 + s;
        iL[s * ROWF2 + ch] = make_float2(xb[gi], yb[gi]);
        const size_t gj = (size_t)(jt * 16 + ch) * Sv + s0 + s;
        jL[s * ROWF2 + ch] = make_float2(xb[gj], yb[gj]);
    }
    __syncthreads();

    const int ti = t >> 4;                     // 0..15: i within tile
    const int tj = t & 15;                     // 0..15: j within tile

    int neg = 0;
    #pragma unroll 8
    for (int s = 0; s < SS; ++s) {
        const float2 a  = jL[s * ROWF2 + tj];  // (x_j, y_j)
        const float2 bi = iL[s * ROWF2 + ti];  // (x_i, y_i)
        const float cr = fmaf(bi.y, a.x, -(bi.x * a.y));
        neg += (int)(__float_as_uint(cr) >> 31);
    }

    const int i = it * 16 + ti;
    const int j = jt * 16 + tj;
    atomicAdd(&out_acc[((size_t)b * Cv + i) * Cv + j], (float)neg);
}

// ---------------------------------------------------------------------------
// Kernel 3: finalize in place. sum_of_signs = S - 2*neg (no exact zeros
// off-diagonal); diagonal forced to exactly 0 (reference: sign(sin(0)) == 0).
// ---------------------------------------------------------------------------
__global__ __launch_bounds__(256) void finalize_kernel(float* __restrict__ out) {
    const int idx = blockIdx.x * 256 + threadIdx.x;     // 65536 = B*C*C
    const int i = (idx >> 6) & 63;
    const int j = idx & 63;
    const float negf = out[idx];
    const float val = (i == j) ? 0.0f
                               : fabsf((float)Sv - 2.0f * negf) * (1.0f / (float)Sv);
    out[idx] = val;
}

extern "C" void kernel_launch(void* const* d_in, const int* in_sizes, int n_in,
                              void* d_out, int out_size, void* d_ws, size_t ws_size,
                              hipStream_t stream) {
    const float* x = (const float*)d_in[0];        // [B, C, S] fp32
    float* y = (float*)d_ws;                       // [B, C, S] fp32 scratch (8 MB)
    float* out = (float*)d_out;                    // [B, C, C] fp32 (also used as accumulator)

    hipLaunchKernelGGL(hilbert_kernel, dim3(Bv * Cv), dim3(256), 0, stream, x, y, out);
    hipLaunchKernelGGL(pli_count_kernel, dim3(Bv * 4 * 4 * SEG), dim3(256), 0, stream, x, y, out);
    hipLaunchKernelGGL(finalize_kernel, dim3(Bv * Cv * Cv / 256), dim3(256), 0, stream, out);
}

// Round 3
// 97.530 us; speedup vs baseline: 2.7346x; 1.2356x over previous
//
#include <hip/hip_runtime.h>

#define Bv 16
#define Cv 64
#define Sv 2048
#define LOG2S 11
#define NSEG 64           // pli segments
#define SSEG 32           // samples per pli segment
#define ROWS 68           // pli LDS row stride in floats (64 ch + 4 pad; 272B = 17*16)

// ---------------------------------------------------------------------------
// Kernel 1: paired-channel Hilbert transform.
//   z = x_a + i*x_b ; Z = fft(z) = X_a + i*X_b ; W = h.*Z ; w = ifft(W)
//   => H(x_a) = Im(w) - x_b ; H(x_b) = x_a - Re(w)
// Forward FFT is DIF (natural in -> bit-rev out); filter applied at k=brev(n);
// inverse is DIT (bit-rev in -> natural out). No bit-reverse permutations, no
// bit-reversed global gather. float2-interleaved LDS => b64 butterflies.
// One block per channel pair (B*C/2 = 512 blocks).
// ---------------------------------------------------------------------------
__global__ __launch_bounds__(256) void hilbert_kernel(const float* __restrict__ x,
                                                      float* __restrict__ y) {
    __shared__ float2 zz[Sv];
    __shared__ float2 Wt[Sv];   // Wt[half+pos] = exp(-i*pi*pos/half)
    const int t = threadIdx.x;
    const int c0 = blockIdx.x * 2;
    const float* x0 = x + (size_t)c0 * Sv;
    const float* x1 = x0 + Sv;

    for (int k = t; k < Sv; k += 256) {
        if (k == 0) { Wt[0] = make_float2(1.0f, 0.0f); continue; }
        const int half = 1 << (31 - __clz(k));
        const int pos = k - half;
        float sn, cs;
        sincosf(-3.14159265358979323846f * (float)pos / (float)half, &sn, &cs);
        Wt[k] = make_float2(cs, sn);
    }
    for (int n = t; n < Sv; n += 256)
        zz[n] = make_float2(x0[n], x1[n]);
    __syncthreads();

    // Forward DIF: butterfly u' = u+v ; v' = (u-v)*w
    for (int half = Sv / 2; half >= 1; half >>= 1) {
        #pragma unroll 4
        for (int q = t; q < Sv / 2; q += 256) {
            const int pos = q & (half - 1);
            const int i0 = 2 * q - pos;
            const int i1 = i0 + half;
            const float2 u = zz[i0], v = zz[i1];
            const float2 w = Wt[half + pos];
            zz[i0] = make_float2(u.x + v.x, u.y + v.y);
            const float dr = u.x - v.x, di = u.y - v.y;
            zz[i1] = make_float2(dr * w.x - di * w.y, dr * w.y + di * w.x);
        }
        __syncthreads();
    }

    // Hilbert multiplier at true frequency k = brev(n): h[0]=h[N/2]=1,
    // h[1..N/2-1]=2, h[N/2+1..]=0
    for (int n = t; n < Sv; n += 256) {
        const int k = (int)(__brev((unsigned)n) >> (32 - LOG2S));
        const float m = (k == 0 || k == Sv / 2) ? 1.0f : (k < Sv / 2 ? 2.0f : 0.0f);
        zz[n].x *= m;
        zz[n].y *= m;
    }
    __syncthreads();

    // Inverse DIT: butterfly v' = v*conj(w) ; u' = u+v' ; l' = u-v'
    for (int half = 1; half < Sv; half <<= 1) {
        #pragma unroll 4
        for (int q = t; q < Sv / 2; q += 256) {
            const int pos = q & (half - 1);
            const int i0 = 2 * q - pos;
            const int i1 = i0 + half;
            const float2 u = zz[i0], v = zz[i1];
            const float2 w = Wt[half + pos];
            const float vr = v.x * w.x + v.y * w.y;     // conj: (cs, -sn)
            const float vi = v.y * w.x - v.x * w.y;
            zz[i0] = make_float2(u.x + vr, u.y + vi);
            zz[i1] = make_float2(u.x - vr, u.y - vi);
        }
        __syncthreads();
    }

    const float inv = 1.0f / (float)Sv;
    for (int n = t; n < Sv; n += 256) {
        const float wr = zz[n].x * inv;
        const float wi = zz[n].y * inv;
        y[(size_t)c0 * Sv + n]       = wi - x1[n];   // H(x_a)
        y[(size_t)(c0 + 1) * Sv + n] = x0[n] - wr;   // H(x_b)
    }
}

// ---------------------------------------------------------------------------
// Kernel 2: PLI negative-sign partial counts. Grid = B * NSEG; block = 256 =
// 16x16 threads, each computing a 4x4 pair tile over 32 samples. One 64-ch
// LDS slab serves both i- and j-fragments (the tile is the whole C x C).
// sign(sin(theta_i - theta_j)) == sign(y_i*x_j - x_i*y_j).
// Writes per-(b,seg) partial counts (no atomics).
// ---------------------------------------------------------------------------
__global__ __launch_bounds__(256) void pli_count_kernel(const float* __restrict__ x,
                                                        const float* __restrict__ y,
                                                        int* __restrict__ part) {
    __shared__ __align__(16) float xL[SSEG * ROWS];
    __shared__ __align__(16) float yL[SSEG * ROWS];
    const int blk = blockIdx.x;                 // b*NSEG + seg
    const int seg = blk & (NSEG - 1);
    const int b = blk >> 6;
    const int t = threadIdx.x;
    const float* xb = x + (size_t)b * Cv * Sv + seg * SSEG;
    const float* yb = y + (size_t)b * Cv * Sv + seg * SSEG;

    // stage 64 ch x 32 samples; lanes: s fast -> coalesced global reads
    for (int e = t; e < Cv * SSEG; e += 256) {
        const int ch = e >> 5;
        const int s = e & (SSEG - 1);
        xL[s * ROWS + ch] = xb[(size_t)ch * Sv + s];
        yL[s * ROWS + ch] = yb[(size_t)ch * Sv + s];
    }
    __syncthreads();

    const int ti = t >> 4, tj = t & 15;
    const int i0 = ti * 4, j0 = tj * 4;
    int neg[4][4] = {};

    #pragma unroll 4
    for (int s = 0; s < SSEG; ++s) {
        const float4 xi = *(const float4*)&xL[s * ROWS + i0];
        const float4 yi = *(const float4*)&yL[s * ROWS + i0];
        const float4 xj = *(const float4*)&xL[s * ROWS + j0];
        const float4 yj = *(const float4*)&yL[s * ROWS + j0];
        const float xia[4] = {xi.x, xi.y, xi.z, xi.w};
        const float yia[4] = {yi.x, yi.y, yi.z, yi.w};
        const float xja[4] = {xj.x, xj.y, xj.z, xj.w};
        const float yja[4] = {yj.x, yj.y, yj.z, yj.w};
        #pragma unroll
        for (int a = 0; a < 4; ++a) {
            #pragma unroll
            for (int c = 0; c < 4; ++c) {
                const float cr = fmaf(yia[a], xja[c], -(xia[a] * yja[c]));
                neg[a][c] += (int)(__float_as_uint(cr) >> 31);
            }
        }
    }

    int* Pb = part + (((size_t)b * NSEG + seg) * Cv) * Cv;   // [b][seg][64][64]
    #pragma unroll
    for (int a = 0; a < 4; ++a) {
        *(int4*)&Pb[(i0 + a) * Cv + j0] =
            make_int4(neg[a][0], neg[a][1], neg[a][2], neg[a][3]);
    }
}

// ---------------------------------------------------------------------------
// Kernel 3: reduce NSEG partials -> PLI. sum_of_signs = S - 2*neg (no exact
// zeros off-diagonal); diagonal forced to exactly 0.
// ---------------------------------------------------------------------------
__global__ __launch_bounds__(256) void finalize_kernel(const int* __restrict__ part,
                                                       float* __restrict__ out) {
    const int idx = blockIdx.x * 256 + threadIdx.x;   // 65536 = B*C*C
    const int b = idx >> 12;
    const int ij = idx & 4095;
    const int* p = part + (size_t)b * NSEG * 4096 + ij;
    int negsum = 0;
    #pragma unroll 8
    for (int s = 0; s < NSEG; ++s) negsum += p[s * 4096];
    const int i = ij >> 6, j = ij & 63;
    out[idx] = (i == j) ? 0.0f
                        : fabsf((float)Sv - 2.0f * (float)negsum) * (1.0f / (float)Sv);
}

extern "C" void kernel_launch(void* const* d_in, const int* in_sizes, int n_in,
                              void* d_out, int out_size, void* d_ws, size_t ws_size,
                              hipStream_t stream) {
    const float* x = (const float*)d_in[0];            // [B, C, S] fp32
    float* y = (float*)d_ws;                           // [B, C, S] fp32 (8 MB)
    int* part = (int*)((char*)d_ws + (size_t)Bv * Cv * Sv * sizeof(float));
    float* out = (float*)d_out;                        // [B, C, C] fp32

    hipLaunchKernelGGL(hilbert_kernel, dim3(Bv * Cv / 2), dim3(256), 0, stream, x, y);
    hipLaunchKernelGGL(pli_count_kernel, dim3(Bv * NSEG), dim3(256), 0, stream, x, y, part);
    hipLaunchKernelGGL(finalize_kernel, dim3(Bv * Cv * Cv / 256), dim3(256), 0, stream, part, out);
}

// Round 4
// 85.527 us; speedup vs baseline: 3.1184x; 1.1403x over previous
//
#include <hip/hip_runtime.h>

#define Bv 16
#define Cv 64
#define Sv 2048
#define NSEG 64           // pli segments
#define SSEG 32           // samples per pli segment
#define ROWS 68           // pli LDS row stride in floats (64 ch + 4 pad)

// Forward DIF butterfly: u' = u+v ; v' = (u-v)*w        (w = Wt[half+pos])
__device__ __forceinline__ void bf_f(float2& u, float2& v, const float2 w) {
    const float dr = u.x - v.x, di = u.y - v.y;
    u.x += v.x; u.y += v.y;
    v.x = dr * w.x - di * w.y;
    v.y = dr * w.y + di * w.x;
}
// Inverse DIT butterfly: v' = v*conj(w) ; u' = u+v' ; l' = u-v'
__device__ __forceinline__ void bf_i(float2& u, float2& v, const float2 w) {
    const float vr = v.x * w.x + v.y * w.y;
    const float vi = v.y * w.x - v.x * w.y;
    v.x = u.x - vr; v.y = u.y - vi;
    u.x += vr; u.y += vi;
}

// ---------------------------------------------------------------------------
// Kernel 1: paired-channel Hilbert transform, register-grouped FFT.
//   z = x_a + i*x_b ; w = ifft(h .* fft(z)) ; H(x_a)=Im(w)-x_b ; H(x_b)=x_a-Re(w)
// 8 complex elements per thread; stage groups run in registers:
//   fwd (1024,512,256)(128,64,32)(16,8)  fused[(4,2,1)+filter/N+(1,2,4)]
//   inv (8,16)(32,64,128)(256,512,1024 -> global store)
// 6 LDS round-trips, 7 barriers (vs 22 stages / 44 barriers).
// One block per channel pair (512 blocks).
// ---------------------------------------------------------------------------
__global__ __launch_bounds__(256) void hilbert_kernel(const float* __restrict__ x,
                                                      float* __restrict__ y) {
    __shared__ float2 zz[Sv];
    __shared__ float2 Wt[Sv];   // Wt[half+pos] = exp(-i*pi*pos/half)
    const int t = threadIdx.x;
    const int c0 = blockIdx.x * 2;
    const float* x0 = x + (size_t)c0 * Sv;
    const float* x1 = x0 + Sv;

    for (int k = t; k < Sv; k += 256) {
        if (k == 0) { Wt[0] = make_float2(1.0f, 0.0f); continue; }
        const int half = 1 << (31 - __clz(k));
        const int pos = k - half;
        float sn, cs;
        sincosf(-3.14159265358979323846f * (float)pos / (float)half, &sn, &cs);
        Wt[k] = make_float2(cs, sn);
    }

    float2 z[8];
    #pragma unroll
    for (int k = 0; k < 8; ++k)
        z[k] = make_float2(x0[t + 256 * k], x1[t + 256 * k]);
    __syncthreads();                 // Wt ready

    // ---- fwd halves 1024,512,256 (stride 256; n_k = t + 256k, global in) ----
    #pragma unroll
    for (int k = 0; k < 4; ++k) bf_f(z[k], z[k + 4], Wt[1024 + t + 256 * k]);
    {
        const float2 wA = Wt[512 + t], wB = Wt[512 + t + 256];
        bf_f(z[0], z[2], wA); bf_f(z[1], z[3], wB);
        bf_f(z[4], z[6], wA); bf_f(z[5], z[7], wB);
        const float2 wc = Wt[256 + t];
        bf_f(z[0], z[1], wc); bf_f(z[2], z[3], wc);
        bf_f(z[4], z[5], wc); bf_f(z[6], z[7], wc);
    }
    #pragma unroll
    for (int k = 0; k < 8; ++k) zz[t + 256 * k] = z[k];
    __syncthreads();

    // ---- fwd halves 128,64,32 (stride 32) ----
    {
        const int r = t & 31, base = (t >> 5) * 256 + r;
        #pragma unroll
        for (int k = 0; k < 8; ++k) z[k] = zz[base + 32 * k];
        #pragma unroll
        for (int k = 0; k < 4; ++k) bf_f(z[k], z[k + 4], Wt[128 + r + 32 * k]);
        const float2 wA = Wt[64 + r], wB = Wt[64 + r + 32];
        bf_f(z[0], z[2], wA); bf_f(z[1], z[3], wB);
        bf_f(z[4], z[6], wA); bf_f(z[5], z[7], wB);
        const float2 wc = Wt[32 + r];
        bf_f(z[0], z[1], wc); bf_f(z[2], z[3], wc);
        bf_f(z[4], z[5], wc); bf_f(z[6], z[7], wc);
        #pragma unroll
        for (int k = 0; k < 8; ++k) zz[base + 32 * k] = z[k];
    }
    __syncthreads();

    // ---- fwd halves 16,8 (stride 8; two 4-sets: z[0..3], z[4..7]) ----
    {
        const int r = t & 7, base0 = (t >> 3) * 32 + r, base1 = base0 + 1024;
        #pragma unroll
        for (int k = 0; k < 4; ++k) { z[k] = zz[base0 + 8 * k]; z[4 + k] = zz[base1 + 8 * k]; }
        const float2 wA = Wt[16 + r], wB = Wt[16 + r + 8];
        bf_f(z[0], z[2], wA); bf_f(z[1], z[3], wB);
        bf_f(z[4], z[6], wA); bf_f(z[5], z[7], wB);
        const float2 wc = Wt[8 + r];
        bf_f(z[0], z[1], wc); bf_f(z[2], z[3], wc);
        bf_f(z[4], z[5], wc); bf_f(z[6], z[7], wc);
        #pragma unroll
        for (int k = 0; k < 4; ++k) { zz[base0 + 8 * k] = z[k]; zz[base1 + 8 * k] = z[4 + k]; }
    }
    __syncthreads();

    // ---- fused: fwd 4,2,1 ; Hilbert filter * 1/N ; inv 1,2,4 (contiguous 8) ----
    {
        const int base = 8 * t;
        #pragma unroll
        for (int k = 0; k < 8; ++k) z[k] = zz[base + k];
        const float cq = 0.70710678118654752f;
        const float2 W1  = make_float2(1.0f, 0.0f);
        const float2 W41 = make_float2(cq, -cq);     // e^{-i pi/4}
        const float2 W42 = make_float2(0.0f, -1.0f); // e^{-i pi/2}
        const float2 W43 = make_float2(-cq, -cq);    // e^{-i 3pi/4}
        // fwd half=4: pairs (k,k+4), pos=k
        bf_f(z[0], z[4], W1);  bf_f(z[1], z[5], W41);
        bf_f(z[2], z[6], W42); bf_f(z[3], z[7], W43);
        // fwd half=2: pairs (k,k+2), pos=k&1
        bf_f(z[0], z[2], W1); bf_f(z[1], z[3], W42);
        bf_f(z[4], z[6], W1); bf_f(z[5], z[7], W42);
        // fwd half=1
        bf_f(z[0], z[1], W1); bf_f(z[2], z[3], W1);
        bf_f(z[4], z[5], W1); bf_f(z[6], z[7], W1);
        // filter at true freq brev11(n), folded with 1/N
        const float inv = 1.0f / (float)Sv;
        #pragma unroll
        for (int k = 0; k < 8; ++k) {
            const int kk = (int)(__brev((unsigned)(base + k)) >> 21);
            const float m = (kk == 0 || kk == Sv / 2) ? inv : (kk < Sv / 2 ? 2.0f * inv : 0.0f);
            z[k].x *= m; z[k].y *= m;
        }
        // inv half=1
        bf_i(z[0], z[1], W1); bf_i(z[2], z[3], W1);
        bf_i(z[4], z[5], W1); bf_i(z[6], z[7], W1);
        // inv half=2: pairs (k,k+2), pos=k&1
        bf_i(z[0], z[2], W1); bf_i(z[1], z[3], W42);
        bf_i(z[4], z[6], W1); bf_i(z[5], z[7], W42);
        // inv half=4: pairs (k,k+4), pos=k
        bf_i(z[0], z[4], W1);  bf_i(z[1], z[5], W41);
        bf_i(z[2], z[6], W42); bf_i(z[3], z[7], W43);
        #pragma unroll
        for (int k = 0; k < 8; ++k) zz[base + k] = z[k];
    }
    __syncthreads();

    // ---- inv halves 8,16 (stride 8; two 4-sets) ----
    {
        const int r = t & 7, base0 = (t >> 3) * 32 + r, base1 = base0 + 1024;
        #pragma unroll
        for (int k = 0; k < 4; ++k) { z[k] = zz[base0 + 8 * k]; z[4 + k] = zz[base1 + 8 * k]; }
        const float2 wc = Wt[8 + r];
        bf_i(z[0], z[1], wc); bf_i(z[2], z[3], wc);
        bf_i(z[4], z[5], wc); bf_i(z[6], z[7], wc);
        const float2 wA = Wt[16 + r], wB = Wt[16 + r + 8];
        bf_i(z[0], z[2], wA); bf_i(z[1], z[3], wB);
        bf_i(z[4], z[6], wA); bf_i(z[5], z[7], wB);
        #pragma unroll
        for (int k = 0; k < 4; ++k) { zz[base0 + 8 * k] = z[k]; zz[base1 + 8 * k] = z[4 + k]; }
    }
    __syncthreads();

    // ---- inv halves 32,64,128 (stride 32) ----
    {
        const int r = t & 31, base = (t >> 5) * 256 + r;
        #pragma unroll
        for (int k = 0; k < 8; ++k) z[k] = zz[base + 32 * k];
        const float2 wc = Wt[32 + r];
        bf_i(z[0], z[1], wc); bf_i(z[2], z[3], wc);
        bf_i(z[4], z[5], wc); bf_i(z[6], z[7], wc);
        const float2 wA = Wt[64 + r], wB = Wt[64 + r + 32];
        bf_i(z[0], z[2], wA); bf_i(z[1], z[3], wB);
        bf_i(z[4], z[6], wA); bf_i(z[5], z[7], wB);
        #pragma unroll
        for (int k = 0; k < 4; ++k) bf_i(z[k], z[k + 4], Wt[128 + r + 32 * k]);
        #pragma unroll
        for (int k = 0; k < 8; ++k) zz[base + 32 * k] = z[k];
    }
    __syncthreads();

    // ---- inv halves 256,512,1024 (stride 256) + fused output write ----
    {
        #pragma unroll
        for (int k = 0; k < 8; ++k) z[k] = zz[t + 256 * k];
        const float2 wc = Wt[256 + t];
        bf_i(z[0], z[1], wc); bf_i(z[2], z[3], wc);
        bf_i(z[4], z[5], wc); bf_i(z[6], z[7], wc);
        const float2 wA = Wt[512 + t], wB = Wt[512 + t + 256];
        bf_i(z[0], z[2], wA); bf_i(z[1], z[3], wB);
        bf_i(z[4], z[6], wA); bf_i(z[5], z[7], wB);
        #pragma unroll
        for (int k = 0; k < 4; ++k) bf_i(z[k], z[k + 4], Wt[1024 + t + 256 * k]);
        float* y0 = y + (size_t)c0 * Sv;
        float* y1 = y0 + Sv;
        #pragma unroll
        for (int k = 0; k < 8; ++k) {
            const int n = t + 256 * k;
            y0[n] = z[k].y - x1[n];   // H(x_a) = Im(w) - x_b
            y1[n] = x0[n] - z[k].x;   // H(x_b) = x_a - Re(w)
        }
    }
}

// ---------------------------------------------------------------------------
// Kernel 2: PLI negative-sign partial counts (unchanged tiling), partials
// packed 4 x u8 per u32 (per-segment count <= 32 fits a byte).
// ---------------------------------------------------------------------------
__global__ __launch_bounds__(256) void pli_count_kernel(const float* __restrict__ x,
                                                        const float* __restrict__ y,
                                                        unsigned int* __restrict__ part) {
    __shared__ __align__(16) float xL[SSEG * ROWS];
    __shared__ __align__(16) float yL[SSEG * ROWS];
    const int blk = blockIdx.x;                 // b*NSEG + seg
    const int seg = blk & (NSEG - 1);
    const int b = blk >> 6;
    const int t = threadIdx.x;
    const float* xb = x + (size_t)b * Cv * Sv + seg * SSEG;
    const float* yb = y + (size_t)b * Cv * Sv + seg * SSEG;

    for (int e = t; e < Cv * SSEG; e += 256) {
        const int ch = e >> 5;
        const int s = e & (SSEG - 1);
        xL[s * ROWS + ch] = xb[(size_t)ch * Sv + s];
        yL[s * ROWS + ch] = yb[(size_t)ch * Sv + s];
    }
    __syncthreads();

    const int ti = t >> 4, tj = t & 15;
    const int i0 = ti * 4, j0 = tj * 4;
    int neg[4][4] = {};

    #pragma unroll 4
    for (int s = 0; s < SSEG; ++s) {
        const float4 xi = *(const float4*)&xL[s * ROWS + i0];
        const float4 yi = *(const float4*)&yL[s * ROWS + i0];
        const float4 xj = *(const float4*)&xL[s * ROWS + j0];
        const float4 yj = *(const float4*)&yL[s * ROWS + j0];
        const float xia[4] = {xi.x, xi.y, xi.z, xi.w};
        const float yia[4] = {yi.x, yi.y, yi.z, yi.w};
        const float xja[4] = {xj.x, xj.y, xj.z, xj.w};
        const float yja[4] = {yj.x, yj.y, yj.z, yj.w};
        #pragma unroll
        for (int a = 0; a < 4; ++a) {
            #pragma unroll
            for (int c = 0; c < 4; ++c) {
                const float cr = fmaf(yia[a], xja[c], -(xia[a] * yja[c]));
                neg[a][c] += (int)(__float_as_uint(cr) >> 31);
            }
        }
    }

    unsigned int* Pb = part + (size_t)(b * NSEG + seg) * (Cv * Cv / 4);  // [64][16] u32
    #pragma unroll
    for (int a = 0; a < 4; ++a) {
        const unsigned int p = (unsigned)neg[a][0] | ((unsigned)neg[a][1] << 8)
                             | ((unsigned)neg[a][2] << 16) | ((unsigned)neg[a][3] << 24);
        Pb[(i0 + a) * (Cv / 4) + tj] = p;
    }
}

// ---------------------------------------------------------------------------
// Kernel 3: unpack + reduce NSEG packed partials -> PLI.
// ---------------------------------------------------------------------------
__global__ __launch_bounds__(256) void finalize_kernel(const unsigned int* __restrict__ part,
                                                       float* __restrict__ out) {
    const int idx = blockIdx.x * 256 + threadIdx.x;   // 65536 = B*C*C
    const int b = idx >> 12;
    const int ij = idx & 4095;
    const int i = ij >> 6, j = ij & 63;
    const unsigned int* p = part + (size_t)b * NSEG * 1024 + i * 16 + (j >> 2);
    const int sh = 8 * (j & 3);
    int negsum = 0;
    #pragma unroll 8
    for (int s = 0; s < NSEG; ++s)
        negsum += (int)((p[s * 1024] >> sh) & 0xFFu);
    out[idx] = (i == j) ? 0.0f
                        : fabsf((float)Sv - 2.0f * (float)negsum) * (1.0f / (float)Sv);
}

extern "C" void kernel_launch(void* const* d_in, const int* in_sizes, int n_in,
                              void* d_out, int out_size, void* d_ws, size_t ws_size,
                              hipStream_t stream) {
    const float* x = (const float*)d_in[0];            // [B, C, S] fp32
    float* y = (float*)d_ws;                           // [B, C, S] fp32 (8 MB)
    unsigned int* part = (unsigned int*)((char*)d_ws + (size_t)Bv * Cv * Sv * sizeof(float));
    float* out = (float*)d_out;                        // [B, C, C] fp32

    hipLaunchKernelGGL(hilbert_kernel, dim3(Bv * Cv / 2), dim3(256), 0, stream, x, y);
    hipLaunchKernelGGL(pli_count_kernel, dim3(Bv * NSEG), dim3(256), 0, stream, x, y, part);
    hipLaunchKernelGGL(finalize_kernel, dim3(Bv * Cv * Cv / 256), dim3(256), 0, stream, part, out);
}